// Round 9
// baseline (4946.902 us; speedup 1.0000x reference)
//
#include <hip/hip_runtime.h>
#include <hip/hip_bf16.h>

#define BB 4
#define MM 8192
#define SS1 2048
#define SS2 512

using ull = unsigned long long;

// ---------------- local branch MLP: pos -> 64 -> 64 -> 128 (tanh each) ----------------
__global__ __launch_bounds__(256) void local_mlp_kernel(
    const float* __restrict__ pos,
    const float* __restrict__ w0, const float* __restrict__ b0,
    const float* __restrict__ w1, const float* __restrict__ b1,
    const float* __restrict__ w2, const float* __restrict__ b2,
    float* __restrict__ out) {
  __shared__ float p[2][3];
  __shared__ float h0[2][64];
  __shared__ float h1[2][64];
  int t = threadIdx.x;
  size_t pid0 = (size_t)blockIdx.x * 2;
  if (t < 6) {
    int pp = t / 3, j = t % 3;
    p[pp][j] = pos[(pid0 + pp) * 3 + j];
  }
  __syncthreads();
  if (t < 128) {
    int pp = t >> 6, c = t & 63;
    float acc = b0[c];
    #pragma unroll
    for (int j = 0; j < 3; ++j) acc += p[pp][j] * w0[j * 64 + c];
    h0[pp][c] = tanhf(acc);
  }
  __syncthreads();
  if (t < 128) {
    int pp = t >> 6, c = t & 63;
    float acc = b1[c];
    #pragma unroll
    for (int j = 0; j < 64; ++j) acc += h0[pp][j] * w1[j * 64 + c];
    h1[pp][c] = tanhf(acc);
  }
  __syncthreads();
  {
    int pp = t >> 7, c = t & 127;
    float acc = b2[c];
    #pragma unroll
    for (int j = 0; j < 64; ++j) acc += h1[pp][j] * w2[j * 128 + c];
    out[(pid0 + pp) * 128 + c] = tanhf(acc);
  }
}

// ---------------- DPP helpers: full-wave max of a u64 key, result in lane 63 ----------
template <int CTRL>
__device__ __forceinline__ void dpp_max_step(ull& k) {
  unsigned lo = (unsigned)k, hi = (unsigned)(k >> 32);
  unsigned plo = (unsigned)__builtin_amdgcn_update_dpp(0, (int)lo, CTRL, 0xF, 0xF, true);
  unsigned phi = (unsigned)__builtin_amdgcn_update_dpp(0, (int)hi, CTRL, 0xF, 0xF, true);
  ull pk = ((ull)phi << 32) | plo;
  if (pk > k) k = pk;
}

__device__ __forceinline__ void wave_max_u64(ull& k) {
  dpp_max_step<0x111>(k);  // row_shr:1
  dpp_max_step<0x112>(k);  // row_shr:2
  dpp_max_step<0x114>(k);  // row_shr:4
  dpp_max_step<0x118>(k);  // row_shr:8
  dpp_max_step<0x142>(k);  // row_bcast:15
  dpp_max_step<0x143>(k);  // row_bcast:31 -> lane63 = wave max
}

// ---------------- farthest point sampling ----------------
// One block per batch. Exact f32 numpy semantics: no fma (contract off,
// x*x then +y*y then +z*z), argmax ties -> lowest index via packed key
// (d2_bits<<32)|~idx. Point coords live in LDS (SoA, strided mapping
// i = t + e*THREADS so ds_read_b32 is conflict-free); the register
// allocator refused to keep them in VGPRs across R5-R8 (VGPR_Count
// 48..84 < required) and re-fetched from L2 every one of 2047 steps.
// Only dd[E] (computed, non-rematerializable) is register-carried.
template <int MP, int NSEL, int THREADS>
__global__ __launch_bounds__(THREADS, 1) void fps_kernel(const float* __restrict__ pts,
                                                         float* __restrict__ cen) {
  constexpr int E = MP / THREADS;
  constexpr int W = THREADS / 64;
  __shared__ float sx[MP];
  __shared__ float sy[MP];
  __shared__ float sz[MP];
  __shared__ ull kb[2][W];
  int t = threadIdx.x;
  int lane = t & 63, wv = t >> 6;
  int b = blockIdx.x;
  const float* p = pts + (size_t)b * MP * 3;
  float* c_out = cen + (size_t)b * NSEL * 3;
  for (int i = t; i < MP; i += THREADS) {
    sx[i] = p[i * 3 + 0];
    sy[i] = p[i * 3 + 1];
    sz[i] = p[i * 3 + 2];
  }
  float dd[E];
  #pragma unroll
  for (int e = 0; e < E; ++e) dd[e] = INFINITY;
  __syncthreads();
  float cx = sx[0], cy = sy[0], cz = sz[0];
  if (t == 0) { c_out[0] = cx; c_out[1] = cy; c_out[2] = cz; }
  int par = 0;
  for (int it = 1; it < NSEL; ++it) {
    float bd = -1.0f;
    int bidx = 0;
    {
      #pragma clang fp contract(off)
      #pragma unroll
      for (int e = 0; e < E; ++e) {
        int i = t + e * THREADS;
        float dx = sx[i] - cx, dy = sy[i] - cy, dz = sz[i] - cz;
        float nd = dx * dx;
        nd += dy * dy;
        nd += dz * dz;
        float d = fminf(dd[e], nd);
        dd[e] = d;
        if (d > bd) { bd = d; bidx = i; }  // strict > keeps lowest index on ties
      }
    }
    ull k = ((ull)__float_as_uint(bd) << 32) | (unsigned)(~bidx);
    wave_max_u64(k);
    if (lane == 63) kb[par][wv] = k;
    __syncthreads();
    ull g = kb[par][0];
    #pragma unroll
    for (int w = 1; w < W; ++w) {
      ull o = kb[par][w];
      if (o > g) g = o;
    }
    int widx = (int)(~(unsigned)g);  // uniform across block
    cx = sx[widx]; cy = sy[widx]; cz = sz[widx];  // LDS broadcast reads
    if (t == 0) {
      c_out[it * 3 + 0] = cx;
      c_out[it * 3 + 1] = cy;
      c_out[it * 3 + 2] = cz;
    }
    par ^= 1;
  }
}

// ---------------- ball query: 64 nearest with d2 <= R2, ties by lower index ----------------
template <int MP>
__global__ __launch_bounds__(256) void nbr_kernel(const float* __restrict__ pts,
                                                  const float* __restrict__ cen, int S,
                                                  float R2, int* __restrict__ nbr) {
  constexpr int CAP = 1024;
  __shared__ ull buf[4][CAP];
  int t = threadIdx.x;
  int wv = t >> 6, lane = t & 63;
  int gw = blockIdx.x * 4 + wv;
  int b = gw / S, s = gw % S;
  const float* p = pts + (size_t)b * MP * 3;
  const float* c = cen + ((size_t)b * S + s) * 3;
  float cx = c[0], cy = c[1], cz = c[2];
  ull* bw = buf[wv];
  int cnt = 0;
  {
    #pragma clang fp contract(off)
    for (int i0 = 0; i0 < MP; i0 += 64) {
      int i = i0 + lane;
      float dx = p[i * 3 + 0] - cx;
      float dy = p[i * 3 + 1] - cy;
      float dz = p[i * 3 + 2] - cz;
      float d2 = dx * dx;
      d2 += dy * dy;
      d2 += dz * dz;
      bool in = (d2 <= R2);
      ull mask = __ballot(in);
      if (in) {
        int off = __popcll(mask & ((1ull << lane) - 1ull));
        int pos = cnt + off;
        if (pos < CAP)
          bw[pos] = ((ull)__float_as_uint(d2) << 32) | (unsigned)i;
      }
      cnt += __popcll(mask);
    }
  }
  if (cnt > CAP) cnt = CAP;
  __syncthreads();  // uniform; ensures LDS writes visible
  int out = -1;
  if (cnt <= 64) {
    if (lane < cnt) out = (int)(unsigned)bw[lane];
  } else {
    for (int r = 0; r < 64; ++r) {
      ull mk = ~0ull;
      int mj = -1;
      for (int j = lane; j < cnt; j += 64) {
        ull v = bw[j];
        if (v < mk) { mk = v; mj = j; }
      }
      ull kc = ~mk;
      wave_max_u64(kc);
      ull g = ~__shfl(kc, 63, 64);
      if (mk == g && mj >= 0) bw[mj] = ~0ull;  // unique keys -> exactly one owner
      asm volatile("s_waitcnt lgkmcnt(0)" ::: "memory");
      if (lane == r) out = (int)(unsigned)g;
    }
  }
  nbr[((size_t)b * S + s) * 64 + lane] = out;
}

// ---------------- SA1 grouped MLP: feats[64][9] -> 64 -> 128, masked max over K ----------------
__global__ __launch_bounds__(128) void group1_kernel(
    const float* __restrict__ pos, const float* __restrict__ x,
    const float* __restrict__ c1, const int* __restrict__ nbr,
    const float* __restrict__ w0, const float* __restrict__ b0,
    const float* __restrict__ w1, const float* __restrict__ b1,
    float* __restrict__ h1out) {
  __shared__ float feats[64][12];
  __shared__ float hbuf[64][66];
  __shared__ int nb[64];
  __shared__ float cc[3];
  int t = threadIdx.x;
  int bs = blockIdx.x;  // b*S1 + s
  int b = bs >> 11;
  if (t < 64) nb[t] = nbr[(size_t)bs * 64 + t];
  if (t < 3) cc[t] = c1[(size_t)bs * 3 + t];
  __syncthreads();
  if (t < 64) {
    int n = nb[t];
    int ni = ((unsigned)n < (unsigned)MM) ? n : 0;  // clamp: replay-safe
    const float* pp = pos + ((size_t)b * MM + ni) * 3;
    const float* xx = x + ((size_t)b * MM + ni) * 3;
    float p0 = pp[0], p1 = pp[1], p2 = pp[2];
    feats[t][0] = p0; feats[t][1] = p1; feats[t][2] = p2;
    feats[t][3] = xx[0]; feats[t][4] = xx[1]; feats[t][5] = xx[2];
    feats[t][6] = p0 - cc[0]; feats[t][7] = p1 - cc[1]; feats[t][8] = p2 - cc[2];
  }
  __syncthreads();
  {
    int k = t >> 1, q = t & 1;
    float acc[32];
    #pragma unroll
    for (int i = 0; i < 32; ++i) acc[i] = b0[q * 32 + i];
    #pragma unroll
    for (int j = 0; j < 9; ++j) {
      float f = feats[k][j];
      #pragma unroll
      for (int i = 0; i < 32; ++i) acc[i] += f * w0[j * 64 + q * 32 + i];
    }
    #pragma unroll
    for (int i = 0; i < 32; ++i) hbuf[k][q * 32 + i] = tanhf(acc[i]);
  }
  __syncthreads();
  {
    int ch = t;  // 0..127
    float w[64];
    #pragma unroll
    for (int j = 0; j < 64; ++j) w[j] = w1[j * 128 + ch];
    float bias = b1[ch];
    float mx = -INFINITY;
    for (int k = 0; k < 64; ++k) {
      if (nb[k] < 0) continue;  // uniform across block
      float a = bias;
      #pragma unroll
      for (int j = 0; j < 64; ++j) a += hbuf[k][j] * w[j];
      mx = fmaxf(mx, tanhf(a));
    }
    h1out[(size_t)bs * 128 + ch] = mx;
  }
}

// ---------------- SA2 grouped MLP: feats[64][131] -> 128 -> 256, masked max over K ----------------
// layer2 is an 8x8 register-tiled GEMM (no w[128] per-thread array).
__global__ __launch_bounds__(256, 4) void group2_kernel(
    const float* __restrict__ h1, const float* __restrict__ c1,
    const float* __restrict__ c2, const int* __restrict__ nbr,
    const float* __restrict__ w0, const float* __restrict__ b0,
    const float* __restrict__ w1, const float* __restrict__ b1,
    float* __restrict__ h2out) {
  __shared__ float fb[64][132];  // feats (131) then reused as hidden (128)
  __shared__ float Mred[8][256];
  __shared__ int nb[64];
  __shared__ float cc[3];
  int t = threadIdx.x;
  int bs = blockIdx.x;  // b*S2 + s
  int b = bs >> 9;
  if (t < 64) nb[t] = nbr[(size_t)bs * 64 + t];
  if (t < 3) cc[t] = c2[(size_t)bs * 3 + t];
  __syncthreads();
  {
    int k = t >> 2, q = t & 3;
    int n = nb[k];
    int ni = ((unsigned)n < (unsigned)SS1) ? n : 0;  // clamp: replay-safe
    const float* hrow = h1 + ((size_t)b * SS1 + ni) * 128;
    #pragma unroll
    for (int i = 0; i < 32; ++i) fb[k][q * 32 + i] = hrow[q * 32 + i];
    if (q == 0) {
      const float* pr = c1 + ((size_t)b * SS1 + ni) * 3;
      fb[k][128] = pr[0] - cc[0];
      fb[k][129] = pr[1] - cc[1];
      fb[k][130] = pr[2] - cc[2];
    }
  }
  __syncthreads();
  float acc1[32];
  {
    int k = t >> 2, q = t & 3;
    #pragma unroll
    for (int i = 0; i < 32; ++i) acc1[i] = b0[q * 32 + i];
    for (int j = 0; j < 131; ++j) {
      float f = fb[k][j];
      const float* wr = w0 + (size_t)j * 128 + q * 32;
      #pragma unroll
      for (int i = 0; i < 32; ++i) acc1[i] += f * wr[i];
    }
  }
  __syncthreads();
  {
    int k = t >> 2, q = t & 3;
    #pragma unroll
    for (int i = 0; i < 32; ++i) fb[k][q * 32 + i] = tanhf(acc1[i]);
  }
  __syncthreads();
  {
    int kt = t >> 5;  // 0..7
    int ct = t & 31;  // 0..31
    float acc[8][8];
    #pragma unroll
    for (int a = 0; a < 8; ++a)
      #pragma unroll
      for (int c2i = 0; c2i < 8; ++c2i) acc[a][c2i] = 0.f;
    const float* wbase = w1 + ct * 8;
    for (int j = 0; j < 128; j += 2) {
      float2 fv[8];
      #pragma unroll
      for (int kk = 0; kk < 8; ++kk)
        fv[kk] = *(const float2*)&fb[kt * 8 + kk][j];
      float wja[8], wjb[8];
      const float4* wp0 = (const float4*)(wbase + (size_t)j * 256);
      const float4* wp1 = (const float4*)(wbase + (size_t)(j + 1) * 256);
      *(float4*)&wja[0] = wp0[0];
      *(float4*)&wja[4] = wp0[1];
      *(float4*)&wjb[0] = wp1[0];
      *(float4*)&wjb[4] = wp1[1];
      #pragma unroll
      for (int kk = 0; kk < 8; ++kk)
        #pragma unroll
        for (int ci = 0; ci < 8; ++ci) {
          acc[kk][ci] += fv[kk].x * wja[ci];
          acc[kk][ci] += fv[kk].y * wjb[ci];
        }
    }
    float bias[8];
    *(float4*)&bias[0] = *(const float4*)(b1 + ct * 8);
    *(float4*)&bias[4] = *(const float4*)(b1 + ct * 8 + 4);
    float m[8];
    #pragma unroll
    for (int ci = 0; ci < 8; ++ci) m[ci] = -INFINITY;
    #pragma unroll
    for (int kk = 0; kk < 8; ++kk) {
      if (nb[kt * 8 + kk] >= 0) {
        #pragma unroll
        for (int ci = 0; ci < 8; ++ci)
          m[ci] = fmaxf(m[ci], tanhf(acc[kk][ci] + bias[ci]));
      }
    }
    #pragma unroll
    for (int ci = 0; ci < 8; ++ci) Mred[kt][ct * 8 + ci] = m[ci];
  }
  __syncthreads();
  if (t < 256) {
    float mx = Mred[0][t];
    #pragma unroll
    for (int r = 1; r < 8; ++r) mx = fmaxf(mx, Mred[r][t]);
    h2out[(size_t)bs * 256 + t] = mx;
  }
}

// ---------------- global max over centers ----------------
__global__ __launch_bounds__(256) void gmax_kernel(const float* __restrict__ h2,
                                                   float* __restrict__ out) {
  int b = blockIdx.x, c = threadIdx.x;
  float mx = -INFINITY;
  for (int s = 0; s < SS2; ++s)
    mx = fmaxf(mx, h2[((size_t)b * SS2 + s) * 256 + c]);
  out[(size_t)BB * MM * 128 + b * 256 + c] = mx;
}

extern "C" void kernel_launch(void* const* d_in, const int* in_sizes, int n_in,
                              void* d_out, int out_size, void* d_ws, size_t ws_size,
                              hipStream_t stream) {
  // Reference is pure float32: all inputs AND the output buffer are f32.
  const float* x    = (const float*)d_in[0];
  const float* pos  = (const float*)d_in[1];
  const float* lw0  = (const float*)d_in[2];
  const float* lb0  = (const float*)d_in[3];
  const float* lw1  = (const float*)d_in[4];
  const float* lb1  = (const float*)d_in[5];
  const float* lw2  = (const float*)d_in[6];
  const float* lb2  = (const float*)d_in[7];
  const float* g1w0 = (const float*)d_in[8];
  const float* g1b0 = (const float*)d_in[9];
  const float* g1w1 = (const float*)d_in[10];
  const float* g1b1 = (const float*)d_in[11];
  const float* g2w0 = (const float*)d_in[12];
  const float* g2b0 = (const float*)d_in[13];
  const float* g2w1 = (const float*)d_in[14];
  const float* g2b1 = (const float*)d_in[15];
  float* out = (float*)d_out;

  // Scratch: prefer d_ws; fall back to the local-output region of d_out
  // (16.8 MB, overwritten by local_mlp which runs LAST).
  const size_t NEED = 9035776;
  char* sc = (ws_size >= NEED) ? (char*)d_ws : (char*)d_out;
  float* h1   = (float*)(sc + 0);        // 4*2048*128 f32 = 4,194,304 B
  float* h2   = (float*)(sc + 4194304);  // 4*512*256 f32  = 2,097,152 B
  float* c1   = (float*)(sc + 6291456);  // 4*2048*3 f32   =    98,304 B
  float* c2   = (float*)(sc + 6389760);  // 4*512*3 f32    =    24,576 B
  int*   nbr1 = (int*)(sc + 6414336);    // 4*2048*64 i32  = 2,097,152 B
  int*   nbr2 = (int*)(sc + 8511488);    // 4*512*64 i32   =   524,288 B (end 9,035,776)

  fps_kernel<MM, SS1, 1024><<<BB, 1024, 0, stream>>>(pos, c1);
  nbr_kernel<MM><<<BB * SS1 / 4, 256, 0, stream>>>(pos, c1, SS1, 0.04f, nbr1);
  group1_kernel<<<BB * SS1, 128, 0, stream>>>(pos, x, c1, nbr1, g1w0, g1b0, g1w1, g1b1, h1);
  fps_kernel<SS1, SS2, 512><<<BB, 512, 0, stream>>>(c1, c2);
  nbr_kernel<SS1><<<BB * SS2 / 4, 256, 0, stream>>>(c1, c2, SS2, 0.16f, nbr2);
  group2_kernel<<<BB * SS2, 256, 0, stream>>>(h1, c1, c2, nbr2, g2w0, g2b0, g2w1, g2b1, h2);
  gmax_kernel<<<BB, 256, 0, stream>>>(h2, out);
  local_mlp_kernel<<<BB * MM / 2, 256, 0, stream>>>(pos, lw0, lb0, lw1, lb1, lw2, lb2, out);
}

// Round 10
// 4250.263 us; speedup vs baseline: 1.1639x; 1.1639x over previous
//
#include <hip/hip_runtime.h>
#include <hip/hip_bf16.h>

#define BB 4
#define MM 8192
#define SS1 2048
#define SS2 512

using ull = unsigned long long;

// ---------------- local branch MLP: pos -> 64 -> 64 -> 128 (tanh each) ----------------
__global__ __launch_bounds__(256) void local_mlp_kernel(
    const float* __restrict__ pos,
    const float* __restrict__ w0, const float* __restrict__ b0,
    const float* __restrict__ w1, const float* __restrict__ b1,
    const float* __restrict__ w2, const float* __restrict__ b2,
    float* __restrict__ out) {
  __shared__ float p[2][3];
  __shared__ float h0[2][64];
  __shared__ float h1[2][64];
  int t = threadIdx.x;
  size_t pid0 = (size_t)blockIdx.x * 2;
  if (t < 6) {
    int pp = t / 3, j = t % 3;
    p[pp][j] = pos[(pid0 + pp) * 3 + j];
  }
  __syncthreads();
  if (t < 128) {
    int pp = t >> 6, c = t & 63;
    float acc = b0[c];
    #pragma unroll
    for (int j = 0; j < 3; ++j) acc += p[pp][j] * w0[j * 64 + c];
    h0[pp][c] = tanhf(acc);
  }
  __syncthreads();
  if (t < 128) {
    int pp = t >> 6, c = t & 63;
    float acc = b1[c];
    #pragma unroll
    for (int j = 0; j < 64; ++j) acc += h0[pp][j] * w1[j * 64 + c];
    h1[pp][c] = tanhf(acc);
  }
  __syncthreads();
  {
    int pp = t >> 7, c = t & 127;
    float acc = b2[c];
    #pragma unroll
    for (int j = 0; j < 64; ++j) acc += h1[pp][j] * w2[j * 128 + c];
    out[(pid0 + pp) * 128 + c] = tanhf(acc);
  }
}

// ---------------- DPP helpers: full-wave max of a u64 key, result in lane 63 ----------
template <int CTRL>
__device__ __forceinline__ void dpp_max_step(ull& k) {
  unsigned lo = (unsigned)k, hi = (unsigned)(k >> 32);
  unsigned plo = (unsigned)__builtin_amdgcn_update_dpp(0, (int)lo, CTRL, 0xF, 0xF, true);
  unsigned phi = (unsigned)__builtin_amdgcn_update_dpp(0, (int)hi, CTRL, 0xF, 0xF, true);
  ull pk = ((ull)phi << 32) | plo;
  if (pk > k) k = pk;
}

__device__ __forceinline__ void wave_max_u64(ull& k) {
  dpp_max_step<0x111>(k);  // row_shr:1
  dpp_max_step<0x112>(k);  // row_shr:2
  dpp_max_step<0x114>(k);  // row_shr:4
  dpp_max_step<0x118>(k);  // row_shr:8
  dpp_max_step<0x142>(k);  // row_bcast:15
  dpp_max_step<0x143>(k);  // row_bcast:31 -> lane63 = wave max
}

// ---------------- farthest point sampling ----------------
// One block per batch. Exact f32 numpy semantics: no fma (contract off,
// x*x then +y*y then +z*z), argmax ties -> lowest index via packed key
// (d2_bits<<32)|~idx. Points in LDS (xy as float2 -> ds_read_b64, z separate;
// strided i = t + e*THREADS is conflict-free). Only dd[E] register-carried.
// 512 threads: 8-wave barrier/reduce overhead < R9's 16-wave version.
template <int MP, int NSEL, int THREADS>
__global__ __launch_bounds__(THREADS, 1) void fps_kernel(const float* __restrict__ pts,
                                                         float* __restrict__ cen) {
  constexpr int E = MP / THREADS;
  constexpr int W = THREADS / 64;
  __shared__ float2 sxy[MP];
  __shared__ float sz[MP];
  __shared__ ull kb[2][W];
  int t = threadIdx.x;
  int lane = t & 63, wv = t >> 6;
  int b = blockIdx.x;
  const float* p = pts + (size_t)b * MP * 3;
  float* c_out = cen + (size_t)b * NSEL * 3;
  for (int i = t; i < MP; i += THREADS) {
    float ax = p[i * 3 + 0], ay = p[i * 3 + 1], az = p[i * 3 + 2];
    sxy[i] = make_float2(ax, ay);
    sz[i] = az;
  }
  float dd[E];
  #pragma unroll
  for (int e = 0; e < E; ++e) dd[e] = INFINITY;
  __syncthreads();
  float cx = sxy[0].x, cy = sxy[0].y, cz = sz[0];
  if (t == 0) { c_out[0] = cx; c_out[1] = cy; c_out[2] = cz; }
  int par = 0;
  for (int it = 1; it < NSEL; ++it) {
    float bd = -1.0f;
    int bidx = 0;
    {
      #pragma clang fp contract(off)
      #pragma unroll
      for (int e = 0; e < E; ++e) {
        int i = t + e * THREADS;
        float2 xy = sxy[i];
        float dx = xy.x - cx, dy = xy.y - cy, dz = sz[i] - cz;
        float nd = dx * dx;
        nd += dy * dy;
        nd += dz * dz;
        float d = fminf(dd[e], nd);
        dd[e] = d;
        if (d > bd) { bd = d; bidx = i; }  // strict > keeps lowest index on ties
      }
    }
    ull k = ((ull)__float_as_uint(bd) << 32) | (unsigned)(~bidx);
    wave_max_u64(k);
    if (lane == 63) kb[par][wv] = k;
    __syncthreads();
    ull g = kb[par][0];
    #pragma unroll
    for (int w = 1; w < W; ++w) {
      ull o = kb[par][w];
      if (o > g) g = o;
    }
    int widx = (int)(~(unsigned)g);  // uniform across block
    float2 cxy = sxy[widx];
    cx = cxy.x; cy = cxy.y; cz = sz[widx];  // LDS broadcast reads
    if (t == 0) {
      c_out[it * 3 + 0] = cx;
      c_out[it * 3 + 1] = cy;
      c_out[it * 3 + 2] = cz;
    }
    par ^= 1;
  }
}

// ---------------- ball query: 64 nearest with d2 <= R2, ties by lower index ----------------
template <int MP>
__global__ __launch_bounds__(256) void nbr_kernel(const float* __restrict__ pts,
                                                  const float* __restrict__ cen, int S,
                                                  float R2, int* __restrict__ nbr) {
  constexpr int CAP = 1024;
  __shared__ ull buf[4][CAP];
  int t = threadIdx.x;
  int wv = t >> 6, lane = t & 63;
  int gw = blockIdx.x * 4 + wv;
  int b = gw / S, s = gw % S;
  const float* p = pts + (size_t)b * MP * 3;
  const float* c = cen + ((size_t)b * S + s) * 3;
  float cx = c[0], cy = c[1], cz = c[2];
  ull* bw = buf[wv];
  int cnt = 0;
  {
    #pragma clang fp contract(off)
    for (int i0 = 0; i0 < MP; i0 += 64) {
      int i = i0 + lane;
      float dx = p[i * 3 + 0] - cx;
      float dy = p[i * 3 + 1] - cy;
      float dz = p[i * 3 + 2] - cz;
      float d2 = dx * dx;
      d2 += dy * dy;
      d2 += dz * dz;
      bool in = (d2 <= R2);
      ull mask = __ballot(in);
      if (in) {
        int off = __popcll(mask & ((1ull << lane) - 1ull));
        int pos = cnt + off;
        if (pos < CAP)
          bw[pos] = ((ull)__float_as_uint(d2) << 32) | (unsigned)i;
      }
      cnt += __popcll(mask);
    }
  }
  if (cnt > CAP) cnt = CAP;
  __syncthreads();  // uniform; ensures LDS writes visible
  int out = -1;
  if (cnt <= 64) {
    if (lane < cnt) out = (int)(unsigned)bw[lane];
  } else {
    for (int r = 0; r < 64; ++r) {
      ull mk = ~0ull;
      int mj = -1;
      for (int j = lane; j < cnt; j += 64) {
        ull v = bw[j];
        if (v < mk) { mk = v; mj = j; }
      }
      ull kc = ~mk;
      wave_max_u64(kc);
      ull g = ~__shfl(kc, 63, 64);
      if (mk == g && mj >= 0) bw[mj] = ~0ull;  // unique keys -> exactly one owner
      asm volatile("s_waitcnt lgkmcnt(0)" ::: "memory");
      if (lane == r) out = (int)(unsigned)g;
    }
  }
  nbr[((size_t)b * S + s) * 64 + lane] = out;
}

// ---------------- SA1 grouped MLP: feats[64][9] -> 64 -> 128, masked max over K ----------------
// layer2 is a register-tiled 8k x 4ch GEMM (no per-thread w[64] array, which
// spilled under __launch_bounds__(128) in R5-R9). tanh is deferred past the
// masked max (monotone; bias k-uniform so it hoists out of the max exactly).
__global__ __launch_bounds__(256, 4) void group1_kernel(
    const float* __restrict__ pos, const float* __restrict__ x,
    const float* __restrict__ c1, const int* __restrict__ nbr,
    const float* __restrict__ w0, const float* __restrict__ b0,
    const float* __restrict__ w1, const float* __restrict__ b1,
    float* __restrict__ h1out) {
  __shared__ float feats[64][12];
  __shared__ float hbuf[64][68];  // 68 floats/row: 8B-aligned rows for float2 reads
  __shared__ float Mred[8][128];
  __shared__ int nb[64];
  __shared__ float cc[3];
  int t = threadIdx.x;
  int bs = blockIdx.x;  // b*S1 + s
  int b = bs >> 11;
  if (t < 64) nb[t] = nbr[(size_t)bs * 64 + t];
  if (t < 3) cc[t] = c1[(size_t)bs * 3 + t];
  __syncthreads();
  if (t < 64) {
    int n = nb[t];
    int ni = ((unsigned)n < (unsigned)MM) ? n : 0;  // clamp: replay-safe
    const float* pp = pos + ((size_t)b * MM + ni) * 3;
    const float* xx = x + ((size_t)b * MM + ni) * 3;
    float p0 = pp[0], p1 = pp[1], p2 = pp[2];
    feats[t][0] = p0; feats[t][1] = p1; feats[t][2] = p2;
    feats[t][3] = xx[0]; feats[t][4] = xx[1]; feats[t][5] = xx[2];
    feats[t][6] = p0 - cc[0]; feats[t][7] = p1 - cc[1]; feats[t][8] = p2 - cc[2];
  }
  __syncthreads();
  // layer1: 9 -> 64; thread (k = t>>2, q = t&3) computes 16 channels
  {
    int k = t >> 2, q = t & 3;
    float acc[16];
    #pragma unroll
    for (int i = 0; i < 16; ++i) acc[i] = b0[q * 16 + i];
    #pragma unroll
    for (int j = 0; j < 9; ++j) {
      float f = feats[k][j];
      #pragma unroll
      for (int i = 0; i < 16; ++i) acc[i] += f * w0[j * 64 + q * 16 + i];
    }
    #pragma unroll
    for (int i = 0; i < 16; ++i) hbuf[k][q * 16 + i] = tanhf(acc[i]);
  }
  __syncthreads();
  // layer2: hidden[64][64] x W1[64][128], tiled: thread (kt=t>>5, ct=t&31)
  // owns k in [8kt,8kt+8), ch in [4ct,4ct+4). Masked PRE-ACT max over k.
  {
    int kt = t >> 5;  // 0..7
    int ct = t & 31;  // 0..31
    float acc[8][4];
    #pragma unroll
    for (int a = 0; a < 8; ++a)
      #pragma unroll
      for (int ci = 0; ci < 4; ++ci) acc[a][ci] = 0.f;
    const float* wbase = w1 + ct * 4;
    for (int j = 0; j < 64; j += 2) {
      float2 fv[8];
      #pragma unroll
      for (int kk = 0; kk < 8; ++kk)
        fv[kk] = *(const float2*)&hbuf[kt * 8 + kk][j];
      float wja[4], wjb[4];
      *(float4*)&wja[0] = *(const float4*)(wbase + (size_t)j * 128);
      *(float4*)&wjb[0] = *(const float4*)(wbase + (size_t)(j + 1) * 128);
      #pragma unroll
      for (int kk = 0; kk < 8; ++kk)
        #pragma unroll
        for (int ci = 0; ci < 4; ++ci) {
          acc[kk][ci] += fv[kk].x * wja[ci];
          acc[kk][ci] += fv[kk].y * wjb[ci];
        }
    }
    float m[4];
    #pragma unroll
    for (int ci = 0; ci < 4; ++ci) m[ci] = -INFINITY;
    #pragma unroll
    for (int kk = 0; kk < 8; ++kk) {
      if (nb[kt * 8 + kk] >= 0) {
        #pragma unroll
        for (int ci = 0; ci < 4; ++ci) m[ci] = fmaxf(m[ci], acc[kk][ci]);
      }
    }
    #pragma unroll
    for (int ci = 0; ci < 4; ++ci) Mred[kt][ct * 4 + ci] = m[ci];
  }
  __syncthreads();
  if (t < 128) {
    float mx = Mred[0][t];
    #pragma unroll
    for (int r = 1; r < 8; ++r) mx = fmaxf(mx, Mred[r][t]);
    h1out[(size_t)bs * 128 + t] = tanhf(mx + b1[t]);  // bias+tanh after max: exact
  }
}

// ---------------- SA2 grouped MLP: feats[64][131] -> 128 -> 256, masked max over K ----------------
// layer2 register-tiled 8x8; tanh+bias deferred past the masked max (exact).
__global__ __launch_bounds__(256, 4) void group2_kernel(
    const float* __restrict__ h1, const float* __restrict__ c1,
    const float* __restrict__ c2, const int* __restrict__ nbr,
    const float* __restrict__ w0, const float* __restrict__ b0,
    const float* __restrict__ w1, const float* __restrict__ b1,
    float* __restrict__ h2out) {
  __shared__ float fb[64][132];  // feats (131) then reused as hidden (128)
  __shared__ float Mred[8][256];
  __shared__ int nb[64];
  __shared__ float cc[3];
  int t = threadIdx.x;
  int bs = blockIdx.x;  // b*S2 + s
  int b = bs >> 9;
  if (t < 64) nb[t] = nbr[(size_t)bs * 64 + t];
  if (t < 3) cc[t] = c2[(size_t)bs * 3 + t];
  __syncthreads();
  {
    int k = t >> 2, q = t & 3;
    int n = nb[k];
    int ni = ((unsigned)n < (unsigned)SS1) ? n : 0;  // clamp: replay-safe
    const float* hrow = h1 + ((size_t)b * SS1 + ni) * 128;
    #pragma unroll
    for (int i = 0; i < 32; ++i) fb[k][q * 32 + i] = hrow[q * 32 + i];
    if (q == 0) {
      const float* pr = c1 + ((size_t)b * SS1 + ni) * 3;
      fb[k][128] = pr[0] - cc[0];
      fb[k][129] = pr[1] - cc[1];
      fb[k][130] = pr[2] - cc[2];
    }
  }
  __syncthreads();
  float acc1[32];
  {
    int k = t >> 2, q = t & 3;
    #pragma unroll
    for (int i = 0; i < 32; ++i) acc1[i] = b0[q * 32 + i];
    for (int j = 0; j < 131; ++j) {
      float f = fb[k][j];
      const float* wr = w0 + (size_t)j * 128 + q * 32;
      #pragma unroll
      for (int i = 0; i < 32; ++i) acc1[i] += f * wr[i];
    }
  }
  __syncthreads();
  {
    int k = t >> 2, q = t & 3;
    #pragma unroll
    for (int i = 0; i < 32; ++i) fb[k][q * 32 + i] = tanhf(acc1[i]);
  }
  __syncthreads();
  {
    int kt = t >> 5;  // 0..7
    int ct = t & 31;  // 0..31
    float acc[8][8];
    #pragma unroll
    for (int a = 0; a < 8; ++a)
      #pragma unroll
      for (int c2i = 0; c2i < 8; ++c2i) acc[a][c2i] = 0.f;
    const float* wbase = w1 + ct * 8;
    for (int j = 0; j < 128; j += 2) {
      float2 fv[8];
      #pragma unroll
      for (int kk = 0; kk < 8; ++kk)
        fv[kk] = *(const float2*)&fb[kt * 8 + kk][j];
      float wja[8], wjb[8];
      const float4* wp0 = (const float4*)(wbase + (size_t)j * 256);
      const float4* wp1 = (const float4*)(wbase + (size_t)(j + 1) * 256);
      *(float4*)&wja[0] = wp0[0];
      *(float4*)&wja[4] = wp0[1];
      *(float4*)&wjb[0] = wp1[0];
      *(float4*)&wjb[4] = wp1[1];
      #pragma unroll
      for (int kk = 0; kk < 8; ++kk)
        #pragma unroll
        for (int ci = 0; ci < 8; ++ci) {
          acc[kk][ci] += fv[kk].x * wja[ci];
          acc[kk][ci] += fv[kk].y * wjb[ci];
        }
    }
    float m[8];
    #pragma unroll
    for (int ci = 0; ci < 8; ++ci) m[ci] = -INFINITY;
    #pragma unroll
    for (int kk = 0; kk < 8; ++kk) {
      if (nb[kt * 8 + kk] >= 0) {
        #pragma unroll
        for (int ci = 0; ci < 8; ++ci) m[ci] = fmaxf(m[ci], acc[kk][ci]);
      }
    }
    #pragma unroll
    for (int ci = 0; ci < 8; ++ci) Mred[kt][ct * 8 + ci] = m[ci];
  }
  __syncthreads();
  if (t < 256) {
    float mx = Mred[0][t];
    #pragma unroll
    for (int r = 1; r < 8; ++r) mx = fmaxf(mx, Mred[r][t]);
    h2out[(size_t)bs * 256 + t] = tanhf(mx + b1[t]);  // bias+tanh after max: exact
  }
}

// ---------------- global max over centers ----------------
__global__ __launch_bounds__(256) void gmax_kernel(const float* __restrict__ h2,
                                                   float* __restrict__ out) {
  int b = blockIdx.x, c = threadIdx.x;
  float mx = -INFINITY;
  for (int s = 0; s < SS2; ++s)
    mx = fmaxf(mx, h2[((size_t)b * SS2 + s) * 256 + c]);
  out[(size_t)BB * MM * 128 + b * 256 + c] = mx;
}

extern "C" void kernel_launch(void* const* d_in, const int* in_sizes, int n_in,
                              void* d_out, int out_size, void* d_ws, size_t ws_size,
                              hipStream_t stream) {
  // Reference is pure float32: all inputs AND the output buffer are f32.
  const float* x    = (const float*)d_in[0];
  const float* pos  = (const float*)d_in[1];
  const float* lw0  = (const float*)d_in[2];
  const float* lb0  = (const float*)d_in[3];
  const float* lw1  = (const float*)d_in[4];
  const float* lb1  = (const float*)d_in[5];
  const float* lw2  = (const float*)d_in[6];
  const float* lb2  = (const float*)d_in[7];
  const float* g1w0 = (const float*)d_in[8];
  const float* g1b0 = (const float*)d_in[9];
  const float* g1w1 = (const float*)d_in[10];
  const float* g1b1 = (const float*)d_in[11];
  const float* g2w0 = (const float*)d_in[12];
  const float* g2b0 = (const float*)d_in[13];
  const float* g2w1 = (const float*)d_in[14];
  const float* g2b1 = (const float*)d_in[15];
  float* out = (float*)d_out;

  // Scratch: prefer d_ws; fall back to the local-output region of d_out
  // (16.8 MB, overwritten by local_mlp which runs LAST).
  const size_t NEED = 9035776;
  char* sc = (ws_size >= NEED) ? (char*)d_ws : (char*)d_out;
  float* h1   = (float*)(sc + 0);        // 4*2048*128 f32 = 4,194,304 B
  float* h2   = (float*)(sc + 4194304);  // 4*512*256 f32  = 2,097,152 B
  float* c1   = (float*)(sc + 6291456);  // 4*2048*3 f32   =    98,304 B
  float* c2   = (float*)(sc + 6389760);  // 4*512*3 f32    =    24,576 B
  int*   nbr1 = (int*)(sc + 6414336);    // 4*2048*64 i32  = 2,097,152 B
  int*   nbr2 = (int*)(sc + 8511488);    // 4*512*64 i32   =   524,288 B (end 9,035,776)

  fps_kernel<MM, SS1, 512><<<BB, 512, 0, stream>>>(pos, c1);
  nbr_kernel<MM><<<BB * SS1 / 4, 256, 0, stream>>>(pos, c1, SS1, 0.04f, nbr1);
  group1_kernel<<<BB * SS1, 256, 0, stream>>>(pos, x, c1, nbr1, g1w0, g1b0, g1w1, g1b1, h1);
  fps_kernel<SS1, SS2, 512><<<BB, 512, 0, stream>>>(c1, c2);
  nbr_kernel<SS1><<<BB * SS2 / 4, 256, 0, stream>>>(c1, c2, SS2, 0.16f, nbr2);
  group2_kernel<<<BB * SS2, 256, 0, stream>>>(h1, c1, c2, nbr2, g2w0, g2b0, g2w1, g2b1, h2);
  gmax_kernel<<<BB, 256, 0, stream>>>(h2, out);
  local_mlp_kernel<<<BB * MM / 2, 256, 0, stream>>>(pos, lw0, lb0, lw1, lb1, lw2, lb2, out);
}